// Round 14
// baseline (380.500 us; speedup 1.0000x reference)
//
#include <hip/hip_runtime.h>
#include <hip/hip_bf16.h>
#include <math.h>

#define NB 2
#define LL 64
#define NMESH 100000
#define HEADS_O 8
#define DHC 64
#define DMODEL 512
#define DINNER 1024
#define DSTATE 64
#define NH 16
#define CONVDIM 1152
#define DINPROJ 2208
#define DOUT 256
#define NCHUNK 6250   // 100000 / 16, exact

typedef __attribute__((ext_vector_type(8))) short short8v;   // 8 x bf16
typedef __attribute__((ext_vector_type(4))) float f32x4;

__device__ __forceinline__ unsigned short f2bf(float f) {
  union { float f; unsigned u; } v; v.f = f;
  unsigned u = v.u;
  u += 0x7FFFu + ((u >> 16) & 1u);
  return (unsigned short)(u >> 16);
}

__device__ __forceinline__ short8v pack_bf16(float4 lo, float4 hi) {
  short8v r;
  r[0] = (short)f2bf(lo.x); r[1] = (short)f2bf(lo.y);
  r[2] = (short)f2bf(lo.z); r[3] = (short)f2bf(lo.w);
  r[4] = (short)f2bf(hi.x); r[5] = (short)f2bf(hi.y);
  r[6] = (short)f2bf(hi.z); r[7] = (short)f2bf(hi.w);
  return r;
}

__device__ __forceinline__ float dot4(float4 a, const float* b) {
  return a.x*b[0] + a.y*b[1] + a.z*b[2] + a.w*b[3];
}

__device__ __forceinline__ float silu(float s) { return s / (1.f + expf(-s)); }

// ---------------------------------------------------------------- K1: in_proj (weight-streaming)
__global__ void k_inproj(const float* __restrict__ st, const float* __restrict__ w,
                         float* __restrict__ zx) {
  int oc = blockIdx.x;             // 0..8 : o = oc*256 + t
  int blc = blockIdx.y;            // 0..15: bl = blc*8 + r
  int t = threadIdx.x;
  __shared__ float u[8][DMODEL];   // 16 KB
  for (int idx = t; idx < 8*DMODEL; idx += 256) {
    int r = idx >> 9, m = idx & 511;
    int bl = blc*8 + r; int b = bl >> 6, l = bl & 63;
    u[r][m] = st[((size_t)(b*HEADS_O + (m >> 6))*LL + l)*DHC + (m & 63)];
  }
  __syncthreads();
  int o = oc*256 + t;
  if (o < DINPROJ) {
    const float4* wr = (const float4*)(w + (size_t)o*DMODEL);
    float acc[8] = {0,0,0,0,0,0,0,0};
    for (int m4 = 0; m4 < DMODEL/4; ++m4) {
      float4 wv = wr[m4];
      #pragma unroll
      for (int r = 0; r < 8; ++r) acc[r] += dot4(wv, &u[r][m4*4]);
    }
    #pragma unroll
    for (int r = 0; r < 8; ++r)
      zx[(size_t)(blc*8 + r)*DINPROJ + o] = acc[r];
  }
}

// ---------------------------------------------------------------- K2: fused conv+silu AND dt softplus
__global__ void k_convdt(const float* __restrict__ zx, const float* __restrict__ cw,
                         const float* __restrict__ cb, const float* __restrict__ dtb,
                         float* __restrict__ conv_out, float* __restrict__ dtbuf) {
  if (blockIdx.x < 576) {
    int i = blockIdx.x*256 + threadIdx.x;           // < 147456
    int c = i % CONVDIM; int l = (i / CONVDIM) % LL; int b = i / (CONVDIM*LL);
    float s = cb[c];
    #pragma unroll
    for (int k = 0; k < 3; ++k) {
      int tt = l - 1 + k;
      if (tt >= 0 && tt < LL)
        s += cw[c*3 + k] * zx[(size_t)(b*LL + tt)*DINPROJ + DINNER + c];
    }
    conv_out[i] = silu(s);
  } else {
    int i = (blockIdx.x - 576)*256 + threadIdx.x;   // (s*64+l)*16+h, 4096 total
    if (i < 4*LL*NH) {
      int h = i & 15, l = (i >> 4) & 63, s = i >> 10;
      float v;
      if (s < 2)
        v = zx[(size_t)(s*LL + l)*DINPROJ + (DINNER + CONVDIM) + h];
      else
        v = zx[(size_t)((s-2)*LL + (63-l))*DINPROJ + (DINNER + CONVDIM) + 16 + h];
      v += dtb[h];
      dtbuf[i] = (v > 20.f) ? v : log1pf(expf(v));
    }
  }
}

// ---------------------------------------------------------------- K3: SSD scan (parallel form)
__global__ void k_scan(const float* __restrict__ conv_out, const float* __restrict__ dtbuf,
                       const float* __restrict__ A_log, float* __restrict__ ybuf) {
  int blk = blockIdx.x;
  int s = blk >> 4, hh = blk & 15;
  int b = s & 1;
  bool rev = (s >= 2);
  int t = threadIdx.x;
  int wv = t >> 6, lane = t & 63;
  __shared__ float Bs[64*68];
  __shared__ float Cs[64*68];
  __shared__ float Xs[64*64];
  __shared__ float dts[64];
  __shared__ float Dc[64];

  for (int id = t; id < 4096; id += 256) {
    int tt0 = id >> 6, n = id & 63;
    int tt = rev ? (63 - tt0) : tt0;
    size_t base = (size_t)(b*LL + tt) * CONVDIM;
    Xs[tt0*64 + n] = conv_out[base + hh*64 + n];
    Bs[tt0*68 + n] = conv_out[base + DINNER + n];
    Cs[tt0*68 + n] = conv_out[base + DINNER + DSTATE + n];
  }
  if (t < 64) dts[t] = dtbuf[(size_t)(s*LL + t)*NH + hh];
  __syncthreads();
  if (t < 64) {
    float v = dts[t];
    #pragma unroll
    for (int m = 1; m < 64; m <<= 1) {
      float o = __shfl_up(v, m, 64);
      if (lane >= m) v += o;
    }
    Dc[t] = v;
  }
  __syncthreads();
  float A = -expf(A_log[hh]);
  float g[16];
  #pragma unroll
  for (int i = 0; i < 16; ++i) {
    int tt = wv + 4*i;
    int ta = lane;
    float gv = 0.f;
    if (ta <= tt) {
      const float* Br = &Bs[ta*68];
      const float* Cr = &Cs[tt*68];
      float dot = 0.f;
      #pragma unroll
      for (int n4 = 0; n4 < 16; ++n4) {
        float4 bv = *(const float4*)&Br[n4*4];
        float4 cv = *(const float4*)&Cr[n4*4];
        dot += bv.x*cv.x + bv.y*cv.y + bv.z*cv.z + bv.w*cv.w;
      }
      gv = dot * expf(A * (Dc[tt] - Dc[ta])) * dts[ta];
    }
    g[i] = gv;
  }
  __syncthreads();
  #pragma unroll
  for (int i = 0; i < 16; ++i) Bs[(wv + 4*i)*64 + lane] = g[i];
  __syncthreads();
  for (int id = t; id < 4096; id += 256) {
    int tt = id >> 6, p = id & 63;
    float y = 0.f;
    for (int ta = 0; ta <= tt; ++ta) y += Bs[tt*64 + ta] * Xs[ta*64 + p];
    ybuf[(size_t)(s*LL + tt)*DINNER + hh*64 + p] = y;
  }
}

// ---------------------------------------------------------------- K4: k_tail = norm + out_proj + mfrag (traffic-neutral merge)
// 32 blocks x 1024 thr, 4 bl-rows per block. Norm phase: 256 thr/row (same
// internal layout as the verified k_norm). Oproj: threads 0..511 each own one
// opw row o=t, loaded ONCE and dotted against all 4 staged rows (opw traffic
// 32x2MB = 64MB, identical to k_oproj; no round-11-style broadcast blowup).
// Mfrag: 8192 frags, 8 per thread (tow 16MB, was 33MB).
__global__ __launch_bounds__(1024) void k_tail(const float* __restrict__ conv_out,
                                               const float* __restrict__ zx,
                                               const float* __restrict__ yb,
                                               const float* __restrict__ fcD,
                                               const float* __restrict__ Dd,
                                               const float* __restrict__ nw,
                                               const float* __restrict__ opw,
                                               const float* __restrict__ tow,
                                               unsigned short* __restrict__ mfp) {
  int bl0 = blockIdx.x * 4;
  int t = threadIdx.x;
  int row = t >> 8, tl = t & 255;
  int bl = bl0 + row; int b = bl >> 6, l = bl & 63;
  __shared__ float xog[4][DINNER];   // 16 KB
  __shared__ float yrow[4][DINNER];  // 16 KB
  __shared__ float ohs[4][DMODEL];   // 8 KB
  __shared__ float diag[4][NH];
  __shared__ float wsum[4][4];

  #pragma unroll
  for (int i = 0; i < 4; ++i) {
    int c = tl + 256*i;
    xog[row][c] = conv_out[(size_t)bl*CONVDIM + c];
  }
  __syncthreads();
  {
    int hh = tl >> 4, j = tl & 15;
    const float* fr = fcD + (size_t)hh*DINNER;
    float acc = 0.f;
    for (int k = 0; k < 64; ++k) acc += xog[row][j + 16*k] * fr[j + 16*k];
    #pragma unroll
    for (int m = 8; m >= 1; m >>= 1) acc += __shfl_xor(acc, m, 64);
    if (j == 0) diag[row][hh] = acc + Dd[hh];
  }
  __syncthreads();
  float ss = 0.f;
  float y2v[4];
  #pragma unroll
  for (int i = 0; i < 4; ++i) {
    int c = tl + 256*i;
    float yf = (l == 0)  ? 0.f : yb[(size_t)(b*LL + l - 1)*DINNER + c];
    float yw = (l == 63) ? 0.f : yb[(size_t)((2+b)*LL + 62 - l)*DINNER + c];
    float y1 = yf + yw + xog[row][c]*diag[row][c >> 6];
    float z = zx[(size_t)bl*DINPROJ + c];
    float y2 = y1 * silu(z);
    y2v[i] = y2;
    ss += y2*y2;
  }
  #pragma unroll
  for (int m = 32; m >= 1; m >>= 1) ss += __shfl_xor(ss, m, 64);
  if ((tl & 63) == 0) wsum[row][tl >> 6] = ss;
  __syncthreads();
  float tot = wsum[row][0] + wsum[row][1] + wsum[row][2] + wsum[row][3];
  float scale = rsqrtf(tot * (1.f/1024.f) + 1e-5f);
  #pragma unroll
  for (int i = 0; i < 4; ++i) {
    int c = tl + 256*i;
    yrow[row][c] = y2v[i] * scale * nw[c];
  }
  __syncthreads();
  // ---- out_proj: threads 0..511, o = t, one opw row -> 4 bl rows
  if (t < 512) {
    const float4* wr = (const float4*)(opw + (size_t)t*DINNER);
    float acc[4] = {0,0,0,0};
    for (int k4 = 0; k4 < DINNER/4; ++k4) {
      float4 wv = wr[k4];
      #pragma unroll
      for (int r = 0; r < 4; ++r) acc[r] += dot4(wv, &yrow[r][k4*4]);
    }
    #pragma unroll
    for (int r = 0; r < 4; ++r) ohs[r][t] = acc[r];
  }
  __syncthreads();
  // ---- mfrag: idx = (r, h, d); 8 per thread
  #pragma unroll
  for (int ii = 0; ii < 8; ++ii) {
    int idx = t + 1024*ii;             // 0..8191
    int r = idx >> 11;
    int h = (idx >> 8) & 7;
    int d = idx & 255;
    const float4* wr = (const float4*)(tow + (size_t)d*DMODEL + h*64);
    const float* op = &ohs[r][h*64];
    float acc = 0.f;
    #pragma unroll
    for (int c4 = 0; c4 < 16; ++c4) acc += dot4(wr[c4], &op[c4*4]);
    int blr = bl0 + r; int br = blr >> 6, g = blr & 63;
    int kk = g >> 5;
    int ln = (d & 15) | (((g & 31) >> 3) << 4);
    int j = g & 7;
    mfp[((((size_t)(br*HEADS_O + h)*2 + kk)*16 + (d >> 4))*64 + ln)*8 + j] = f2bf(acc);
  }
}

// ---------------------------------------------------------------- K5: amplification-1x GEMM, 2 chunks per barrier phase
// As round 12 (convert-once bf16 A-share, B in regs, W crosses fabric once)
// but each barrier phase covers TWO chunks (c, c+128): 64 KB LDS dbuf of
// chunk-pairs, 1-deep reg staging (sets A,B = next pair, issued at phase
// start, converted at phase end -> full-phase window). Barriers 49 -> 25.
__global__ __launch_bounds__(512, 1) void k_out_gemm(const float* __restrict__ W,
                                                     const unsigned short* __restrict__ mf,
                                                     const float* __restrict__ tob,
                                                     float* __restrict__ out) {
  int bx = blockIdx.x;
  int b    = bx >> 7;
  int base = bx & 127;
  int tid = threadIdx.x;
  int wv = tid >> 6, lane = tid & 63;
  int r16 = lane & 15, kg = lane >> 4;

  __shared__ __align__(16) unsigned short lsA[2][2][16][512];  // [buf][slot][ks][512] = 64 KB

  short8v B0[16], B1[16];
  {
    const unsigned short* mfb = mf + (size_t)b*(16*16*512) + lane*8;
    #pragma unroll
    for (int ks = 0; ks < 16; ++ks) {
      B0[ks] = *(const short8v*)(mfb + ((size_t)ks*16 + 2*wv    )*512);
      B1[ks] = *(const short8v*)(mfb + ((size_t)ks*16 + 2*wv + 1)*512);
    }
  }
  float bias0 = tob[wv*32 + r16];
  float bias1 = tob[wv*32 + 16 + r16];

  const float* wbase = W + ((size_t)(b*HEADS_O + wv)*NMESH + r16)*64 + kg*8;

  float4 a0, a1, a2, a3;   // reg set A (chunk slot 0 of next pair)
  float4 b0, b1, b2, b3;   // reg set B (chunk slot 1 of next pair)

  #define ALOADS(cc, v0, v1, v2, v3) do { \
    const float* p0 = wbase + (size_t)(cc)*1024; \
    v0 = *(const float4*)p0;        v1 = *(const float4*)(p0 + 4); \
    v2 = *(const float4*)(p0 + 32); v3 = *(const float4*)(p0 + 36); \
  } while (0)
  #define AWR(pp, sl, v0, v1, v2, v3) do { \
    *(short8v*)&lsA[pp][sl][2*wv    ][lane*8] = pack_bf16(v0, v1); \
    *(short8v*)&lsA[pp][sl][2*wv + 1][lane*8] = pack_bf16(v2, v3); \
  } while (0)
  #define MFMA_STORE(pp, sl, cc) do { \
    f32x4 acc0 = (f32x4){0.f,0.f,0.f,0.f}; \
    f32x4 acc1 = (f32x4){0.f,0.f,0.f,0.f}; \
    _Pragma("unroll") \
    for (int ks = 0; ks < 16; ++ks) { \
      short8v af = *(const short8v*)&lsA[pp][sl][ks][lane*8]; \
      acc0 = __builtin_amdgcn_mfma_f32_16x16x32_bf16(af, B0[ks], acc0, 0, 0, 0); \
      acc1 = __builtin_amdgcn_mfma_f32_16x16x32_bf16(af, B1[ks], acc1, 0, 0, 0); \
    } \
    int rb = (cc)*16 + kg*4; \
    int cg = wv*32 + r16; \
    _Pragma("unroll") \
    for (int r = 0; r < 4; ++r) { \
      out[((size_t)b*NMESH + rb + r)*DOUT + cg]      = acc0[r] + bias0; \
      out[((size_t)b*NMESH + rb + r)*DOUT + cg + 16] = acc1[r] + bias1; \
    } \
  } while (0)
  #define KBAR() do { \
    asm volatile("s_waitcnt lgkmcnt(0)" ::: "memory"); \
    __builtin_amdgcn_sched_barrier(0); \
    __builtin_amdgcn_s_barrier(); \
    __builtin_amdgcn_sched_barrier(0); \
  } while (0)

  // ---- prologue: pair (base, base+128) -> buf 0 (base+128 < 6250 always)
  ALOADS(base, a0, a1, a2, a3);
  AWR(0, 0, a0, a1, a2, a3);
  ALOADS(base + 128, b0, b1, b2, b3);
  AWR(0, 1, b0, b1, b2, b3);
  KBAR();

  int c = base;
  int p = 0;
  for (;;) {
    int cn = c + 256;
    bool more = (cn < NCHUNK);
    if (more) {
      ALOADS(cn, a0, a1, a2, a3);                       // next pair slot 0
      if (cn + 128 < NCHUNK) ALOADS(cn + 128, b0, b1, b2, b3);  // slot 1
    }
    __builtin_amdgcn_sched_barrier(0);
    MFMA_STORE(p, 0, c);
    if (c + 128 < NCHUNK) MFMA_STORE(p, 1, c + 128);
    if (!more) break;
    __builtin_amdgcn_sched_barrier(0);
    AWR(p ^ 1, 0, a0, a1, a2, a3);
    if (cn + 128 < NCHUNK) AWR(p ^ 1, 1, b0, b1, b2, b3);
    KBAR();
    p ^= 1; c = cn;
  }
  #undef ALOADS
  #undef AWR
  #undef MFMA_STORE
  #undef KBAR
}

// ----------------------------------------------------------------
extern "C" void kernel_launch(void* const* d_in, const int* in_sizes, int n_in,
                              void* d_out, int out_size, void* d_ws, size_t ws_size,
                              hipStream_t stream) {
  (void)in_sizes; (void)n_in; (void)out_size; (void)ws_size;
  const float* st   = (const float*)d_in[0];
  const float* sw   = (const float*)d_in[1];
  const float* ipw  = (const float*)d_in[2];
  const float* cw   = (const float*)d_in[3];
  const float* cb   = (const float*)d_in[4];
  const float* dtb  = (const float*)d_in[5];
  const float* alog = (const float*)d_in[6];
  const float* fcD  = (const float*)d_in[7];
  const float* Dd   = (const float*)d_in[8];
  const float* nw   = (const float*)d_in[9];
  const float* opw  = (const float*)d_in[10];
  const float* tow  = (const float*)d_in[11];
  const float* tob  = (const float*)d_in[12];
  float* out = (float*)d_out;
  unsigned char* ws = (unsigned char*)d_ws;

  float* zx   = (float*)(ws + 0);            // 2*64*2208*4 = 1130496
  float* conv = (float*)(ws + 1130496);      // 2*64*1152*4 = 589824
  float* dtp  = (float*)(ws + 1720320);      // 4*64*16*4   = 16384
  float* yb   = (float*)(ws + 1736704);      // 4*64*1024*4 = 1048576
  unsigned short* mfr = (unsigned short*)(ws + 2785280);  // 524288

  k_inproj  <<<dim3(9, 16), 256, 0, stream>>>(st, ipw, zx);
  k_convdt  <<<592, 256, 0, stream>>>(zx, cw, cb, dtb, conv, dtp);
  k_scan    <<<64,  256, 0, stream>>>(conv, dtp, alog, yb);
  k_tail    <<<32, 1024, 0, stream>>>(conv, zx, yb, fcD, Dd, nw, opw, tow, mfr);
  k_out_gemm<<<256, 512, 0, stream>>>(sw, mfr, tob, out);
}

// Round 15
// 245.051 us; speedup vs baseline: 1.5527x; 1.5527x over previous
//
#include <hip/hip_runtime.h>
#include <hip/hip_bf16.h>
#include <math.h>

#define NB 2
#define LL 64
#define NMESH 100000
#define HEADS_O 8
#define DHC 64
#define DMODEL 512
#define DINNER 1024
#define DSTATE 64
#define NH 16
#define CONVDIM 1152
#define DINPROJ 2208
#define DOUT 256
#define NC32 3125     // 100000 / 32, exact

typedef __attribute__((ext_vector_type(8))) short short8v;   // 8 x bf16
typedef __attribute__((ext_vector_type(4))) float f32x4;

__device__ __forceinline__ unsigned short f2bf(float f) {
  union { float f; unsigned u; } v; v.f = f;
  unsigned u = v.u;
  u += 0x7FFFu + ((u >> 16) & 1u);
  return (unsigned short)(u >> 16);
}

__device__ __forceinline__ short8v pack_bf16(float4 lo, float4 hi) {
  short8v r;
  r[0] = (short)f2bf(lo.x); r[1] = (short)f2bf(lo.y);
  r[2] = (short)f2bf(lo.z); r[3] = (short)f2bf(lo.w);
  r[4] = (short)f2bf(hi.x); r[5] = (short)f2bf(hi.y);
  r[6] = (short)f2bf(hi.z); r[7] = (short)f2bf(hi.w);
  return r;
}

__device__ __forceinline__ float dot4(float4 a, const float* b) {
  return a.x*b[0] + a.y*b[1] + a.z*b[2] + a.w*b[3];
}

__device__ __forceinline__ float silu(float s) { return s / (1.f + expf(-s)); }

// ---------------------------------------------------------------- K1: in_proj (weight-streaming)
__global__ void k_inproj(const float* __restrict__ st, const float* __restrict__ w,
                         float* __restrict__ zx) {
  int oc = blockIdx.x;             // 0..8 : o = oc*256 + t
  int blc = blockIdx.y;            // 0..15: bl = blc*8 + r
  int t = threadIdx.x;
  __shared__ float u[8][DMODEL];   // 16 KB
  for (int idx = t; idx < 8*DMODEL; idx += 256) {
    int r = idx >> 9, m = idx & 511;
    int bl = blc*8 + r; int b = bl >> 6, l = bl & 63;
    u[r][m] = st[((size_t)(b*HEADS_O + (m >> 6))*LL + l)*DHC + (m & 63)];
  }
  __syncthreads();
  int o = oc*256 + t;
  if (o < DINPROJ) {
    const float4* wr = (const float4*)(w + (size_t)o*DMODEL);
    float acc[8] = {0,0,0,0,0,0,0,0};
    for (int m4 = 0; m4 < DMODEL/4; ++m4) {
      float4 wv = wr[m4];
      #pragma unroll
      for (int r = 0; r < 8; ++r) acc[r] += dot4(wv, &u[r][m4*4]);
    }
    #pragma unroll
    for (int r = 0; r < 8; ++r)
      zx[(size_t)(blc*8 + r)*DINPROJ + o] = acc[r];
  }
}

// ---------------------------------------------------------------- K2: fused conv+silu AND dt softplus
__global__ void k_convdt(const float* __restrict__ zx, const float* __restrict__ cw,
                         const float* __restrict__ cb, const float* __restrict__ dtb,
                         float* __restrict__ conv_out, float* __restrict__ dtbuf) {
  if (blockIdx.x < 576) {
    int i = blockIdx.x*256 + threadIdx.x;           // < 147456
    int c = i % CONVDIM; int l = (i / CONVDIM) % LL; int b = i / (CONVDIM*LL);
    float s = cb[c];
    #pragma unroll
    for (int k = 0; k < 3; ++k) {
      int tt = l - 1 + k;
      if (tt >= 0 && tt < LL)
        s += cw[c*3 + k] * zx[(size_t)(b*LL + tt)*DINPROJ + DINNER + c];
    }
    conv_out[i] = silu(s);
  } else {
    int i = (blockIdx.x - 576)*256 + threadIdx.x;   // (s*64+l)*16+h, 4096 total
    if (i < 4*LL*NH) {
      int h = i & 15, l = (i >> 4) & 63, s = i >> 10;
      float v;
      if (s < 2)
        v = zx[(size_t)(s*LL + l)*DINPROJ + (DINNER + CONVDIM) + h];
      else
        v = zx[(size_t)((s-2)*LL + (63-l))*DINPROJ + (DINNER + CONVDIM) + 16 + h];
      v += dtb[h];
      dtbuf[i] = (v > 20.f) ? v : log1pf(expf(v));
    }
  }
}

// ---------------------------------------------------------------- K3: SSD scan (parallel form)
__global__ void k_scan(const float* __restrict__ conv_out, const float* __restrict__ dtbuf,
                       const float* __restrict__ A_log, float* __restrict__ ybuf) {
  int blk = blockIdx.x;
  int s = blk >> 4, hh = blk & 15;
  int b = s & 1;
  bool rev = (s >= 2);
  int t = threadIdx.x;
  int wv = t >> 6, lane = t & 63;
  __shared__ float Bs[64*68];
  __shared__ float Cs[64*68];
  __shared__ float Xs[64*64];
  __shared__ float dts[64];
  __shared__ float Dc[64];

  for (int id = t; id < 4096; id += 256) {
    int tt0 = id >> 6, n = id & 63;
    int tt = rev ? (63 - tt0) : tt0;
    size_t base = (size_t)(b*LL + tt) * CONVDIM;
    Xs[tt0*64 + n] = conv_out[base + hh*64 + n];
    Bs[tt0*68 + n] = conv_out[base + DINNER + n];
    Cs[tt0*68 + n] = conv_out[base + DINNER + DSTATE + n];
  }
  if (t < 64) dts[t] = dtbuf[(size_t)(s*LL + t)*NH + hh];
  __syncthreads();
  if (t < 64) {
    float v = dts[t];
    #pragma unroll
    for (int m = 1; m < 64; m <<= 1) {
      float o = __shfl_up(v, m, 64);
      if (lane >= m) v += o;
    }
    Dc[t] = v;
  }
  __syncthreads();
  float A = -expf(A_log[hh]);
  float g[16];
  #pragma unroll
  for (int i = 0; i < 16; ++i) {
    int tt = wv + 4*i;
    int ta = lane;
    float gv = 0.f;
    if (ta <= tt) {
      const float* Br = &Bs[ta*68];
      const float* Cr = &Cs[tt*68];
      float dot = 0.f;
      #pragma unroll
      for (int n4 = 0; n4 < 16; ++n4) {
        float4 bv = *(const float4*)&Br[n4*4];
        float4 cv = *(const float4*)&Cr[n4*4];
        dot += bv.x*cv.x + bv.y*cv.y + bv.z*cv.z + bv.w*cv.w;
      }
      gv = dot * expf(A * (Dc[tt] - Dc[ta])) * dts[ta];
    }
    g[i] = gv;
  }
  __syncthreads();
  #pragma unroll
  for (int i = 0; i < 16; ++i) Bs[(wv + 4*i)*64 + lane] = g[i];
  __syncthreads();
  for (int id = t; id < 4096; id += 256) {
    int tt = id >> 6, p = id & 63;
    float y = 0.f;
    for (int ta = 0; ta <= tt; ++ta) y += Bs[tt*64 + ta] * Xs[ta*64 + p];
    ybuf[(size_t)(s*LL + tt)*DINNER + hh*64 + p] = y;
  }
}

// ---------------------------------------------------------------- K4: combine + gate + RMSnorm -> ynorm
__global__ void k_norm(const float* __restrict__ conv_out, const float* __restrict__ zx,
                       const float* __restrict__ yb, const float* __restrict__ fcD,
                       const float* __restrict__ Dd, const float* __restrict__ nw,
                       float* __restrict__ ynorm) {
  int bl = blockIdx.x; int b = bl >> 6, l = bl & 63;
  int t = threadIdx.x;
  __shared__ float xog[DINNER];
  __shared__ float diag[NH];
  __shared__ float wsum[4];
  size_t base = (size_t)bl * CONVDIM;
  for (int c = t; c < DINNER; c += 256) xog[c] = conv_out[base + c];
  __syncthreads();
  {
    int hh = t >> 4, j = t & 15;
    const float* fr = fcD + (size_t)hh*DINNER;
    float acc = 0.f;
    for (int k = 0; k < 64; ++k) acc += xog[j + 16*k] * fr[j + 16*k];
    #pragma unroll
    for (int m = 8; m >= 1; m >>= 1) acc += __shfl_xor(acc, m, 64);
    if (j == 0) diag[hh] = acc + Dd[hh];
  }
  __syncthreads();
  float ss = 0.f;
  float y2v[4];
  #pragma unroll
  for (int i = 0; i < 4; ++i) {
    int c = t + 256*i;
    float yf = (l == 0)  ? 0.f : yb[(size_t)(b*LL + l - 1)*DINNER + c];
    float yw = (l == 63) ? 0.f : yb[(size_t)((2+b)*LL + 62 - l)*DINNER + c];
    float y1 = yf + yw + xog[c]*diag[c >> 6];
    float z = zx[(size_t)bl*DINPROJ + c];
    float y2 = y1 * silu(z);
    y2v[i] = y2;
    ss += y2*y2;
  }
  #pragma unroll
  for (int m = 32; m >= 1; m >>= 1) ss += __shfl_xor(ss, m, 64);
  if ((t & 63) == 0) wsum[t >> 6] = ss;
  __syncthreads();
  float tot = wsum[0] + wsum[1] + wsum[2] + wsum[3];
  float scale = rsqrtf(tot * (1.f/1024.f) + 1e-5f);
  #pragma unroll
  for (int i = 0; i < 4; ++i) {
    int c = t + 256*i;
    ynorm[(size_t)bl*DINNER + c] = y2v[i] * scale * nw[c];
  }
}

// ---------------------------------------------------------------- K5: out_proj (weight-streaming)
__global__ void k_oproj(const float* __restrict__ ynorm, const float* __restrict__ opw,
                        float* __restrict__ oh) {
  int oc = blockIdx.x;            // 0..1 : o = oc*256 + t
  int blc = blockIdx.y;           // 0..31: bl = blc*4 + r
  int t = threadIdx.x;
  __shared__ float yr[4][DINNER]; // 16 KB
  for (int idx = t; idx < 4*DINNER; idx += 256) {
    int r = idx >> 10, k = idx & 1023;
    yr[r][k] = ynorm[(size_t)(blc*4 + r)*DINNER + k];
  }
  __syncthreads();
  int o = oc*256 + t;
  const float4* wr = (const float4*)(opw + (size_t)o*DINNER);
  float acc[4] = {0,0,0,0};
  for (int k4 = 0; k4 < DINNER/4; ++k4) {
    float4 wv = wr[k4];
    #pragma unroll
    for (int r = 0; r < 4; ++r) acc[r] += dot4(wv, &yr[r][k4*4]);
  }
  #pragma unroll
  for (int r = 0; r < 4; ++r)
    oh[(size_t)(blc*4 + r)*DMODEL + o] = acc[r];
}

// ---------------------------------------------------------------- K6: build M in B-fragment order (bf16)
__global__ void k_mfrag(const float* __restrict__ oh, const float* __restrict__ tow,
                        unsigned short* __restrict__ mfp) {
  int bgc = blockIdx.x;            // 0..15, bg = bgc*8 + r
  int dc  = blockIdx.y;            // 0..3 : d = dc*64 + dl
  int t = threadIdx.x;
  __shared__ float orow[8][DMODEL]; // 16 KB
  for (int idx = t; idx < 8*DMODEL; idx += 256) {
    int r = idx >> 9, m = idx & 511;
    orow[r][m] = oh[(size_t)(bgc*8 + r)*DMODEL + m];
  }
  __syncthreads();
  #pragma unroll
  for (int ii = 0; ii < 2; ++ii) {
    int idx = t + 256*ii;          // 0..511 -> (h, dl)
    int h = idx >> 6, dl = idx & 63;
    int d = dc*64 + dl;
    const float4* wr = (const float4*)(tow + (size_t)d*DMODEL + h*64);
    float acc[8] = {0,0,0,0,0,0,0,0};
    #pragma unroll
    for (int c4 = 0; c4 < 16; ++c4) {
      float4 wv = wr[c4];
      #pragma unroll
      for (int r = 0; r < 8; ++r) acc[r] += dot4(wv, &orow[r][h*64 + c4*4]);
    }
    #pragma unroll
    for (int r = 0; r < 8; ++r) {
      int bg = bgc*8 + r; int b = bg >> 6, g = bg & 63;
      int kk = g >> 5;
      int ln = (d & 15) | (((g & 31) >> 3) << 4);
      int j = g & 7;
      mfp[((((size_t)(b*HEADS_O + h)*2 + kk)*16 + (d >> 4))*64 + ln)*8 + j] = f2bf(acc[r]);
    }
  }
}

// ---------------------------------------------------------------- K7: amplification-1x GEMM, 32-row chunks (25 phases)
// As round 12 (convert-once bf16 A-share, B in regs, W crosses fabric once)
// but chunk = 32 rows (2 row-tiles per wave per phase): per-phase HBM demand
// doubles (64 KB loads + 32 KB stores) against constant per-phase fixed costs
// -> higher memory duty cycle; barriers 49 -> 25. 1-deep staging (8 float4 =
// 32 VGPR; audited total ~200, no spill). Grid 250 = 2b x 125 base; every
// block runs exactly 25 uniform iterations (3125 = 25*125 chunk32s).
__global__ __launch_bounds__(512, 1) void k_out_gemm(const float* __restrict__ W,
                                                     const unsigned short* __restrict__ mf,
                                                     const float* __restrict__ tob,
                                                     float* __restrict__ out) {
  int bx = blockIdx.x;
  int b    = bx / 125;
  int base = bx % 125;
  int tid = threadIdx.x;
  int wv = tid >> 6, lane = tid & 63;
  int r16 = lane & 15, kg = lane >> 4;

  __shared__ __align__(16) unsigned short lsA[2][2][16][512];  // [buf][rt][ks][512] = 64 KB

  // ---- B fragments into registers: wave wv owns ct = 2wv, 2wv+1
  short8v B0[16], B1[16];
  {
    const unsigned short* mfb = mf + (size_t)b*(16*16*512) + lane*8;
    #pragma unroll
    for (int ks = 0; ks < 16; ++ks) {
      B0[ks] = *(const short8v*)(mfb + ((size_t)ks*16 + 2*wv    )*512);
      B1[ks] = *(const short8v*)(mfb + ((size_t)ks*16 + 2*wv + 1)*512);
    }
  }
  float bias0 = tob[wv*32 + r16];
  float bias1 = tob[wv*32 + 16 + r16];

  // stager: wave wv = head wv; k-steps 2wv (kk=0), 2wv+1 (kk=1); 2 row-tiles
  const float* wbase = W + ((size_t)(b*HEADS_O + wv)*NMESH + r16)*64 + kg*8;

  float4 t0, t1, t2, t3, t4, t5, t6, t7;   // rt0: kk0(lo,hi) kk1(lo,hi); rt1: same

  #define ALOADS(CC) do { \
    const float* p0 = wbase + (size_t)(CC)*2048; \
    t0 = *(const float4*)p0;          t1 = *(const float4*)(p0 + 4); \
    t2 = *(const float4*)(p0 + 32);   t3 = *(const float4*)(p0 + 36); \
    t4 = *(const float4*)(p0 + 1024); t5 = *(const float4*)(p0 + 1028); \
    t6 = *(const float4*)(p0 + 1056); t7 = *(const float4*)(p0 + 1060); \
  } while (0)
  #define AWR(pp) do { \
    *(short8v*)&lsA[pp][0][2*wv    ][lane*8] = pack_bf16(t0, t1); \
    *(short8v*)&lsA[pp][0][2*wv + 1][lane*8] = pack_bf16(t2, t3); \
    *(short8v*)&lsA[pp][1][2*wv    ][lane*8] = pack_bf16(t4, t5); \
    *(short8v*)&lsA[pp][1][2*wv + 1][lane*8] = pack_bf16(t6, t7); \
  } while (0)
  #define KBAR() do { \
    asm volatile("s_waitcnt lgkmcnt(0)" ::: "memory"); \
    __builtin_amdgcn_sched_barrier(0); \
    __builtin_amdgcn_s_barrier(); \
    __builtin_amdgcn_sched_barrier(0); \
  } while (0)

  // ---- prologue: chunk32 `base` -> buf 0
  ALOADS(base);
  AWR(0);
  KBAR();

  int C = base;
  int p = 0;
  for (;;) {
    int Cn = C + 125;
    bool more = (Cn < NC32);
    if (more) ALOADS(Cn);                 // next chunk32, consumed at AWR below
    __builtin_amdgcn_sched_barrier(0);

    f32x4 a00 = (f32x4){0.f,0.f,0.f,0.f};
    f32x4 a01 = (f32x4){0.f,0.f,0.f,0.f};
    f32x4 a10 = (f32x4){0.f,0.f,0.f,0.f};
    f32x4 a11 = (f32x4){0.f,0.f,0.f,0.f};
    #pragma unroll
    for (int ks = 0; ks < 16; ++ks) {
      short8v af0 = *(const short8v*)&lsA[p][0][ks][lane*8];
      short8v af1 = *(const short8v*)&lsA[p][1][ks][lane*8];
      a00 = __builtin_amdgcn_mfma_f32_16x16x32_bf16(af0, B0[ks], a00, 0, 0, 0);
      a01 = __builtin_amdgcn_mfma_f32_16x16x32_bf16(af0, B1[ks], a01, 0, 0, 0);
      a10 = __builtin_amdgcn_mfma_f32_16x16x32_bf16(af1, B0[ks], a10, 0, 0, 0);
      a11 = __builtin_amdgcn_mfma_f32_16x16x32_bf16(af1, B1[ks], a11, 0, 0, 0);
    }

    // stores: col=lane&15, row=kg*4+r; rt0 rows C*32+kg*4, rt1 +16
    {
      int rb0 = C*32 + kg*4;
      int cg = wv*32 + r16;
      #pragma unroll
      for (int r = 0; r < 4; ++r) {
        size_t ro0 = ((size_t)b*NMESH + rb0 + r)*DOUT;
        size_t ro1 = ((size_t)b*NMESH + rb0 + 16 + r)*DOUT;
        out[ro0 + cg]      = a00[r] + bias0;
        out[ro0 + cg + 16] = a01[r] + bias1;
        out[ro1 + cg]      = a10[r] + bias0;
        out[ro1 + cg + 16] = a11[r] + bias1;
      }
    }

    if (!more) break;
    __builtin_amdgcn_sched_barrier(0);
    AWR(p ^ 1);                           // convert once, share
    KBAR();
    p ^= 1;
    C = Cn;
  }
  #undef ALOADS
  #undef AWR
  #undef KBAR
}

// ----------------------------------------------------------------
extern "C" void kernel_launch(void* const* d_in, const int* in_sizes, int n_in,
                              void* d_out, int out_size, void* d_ws, size_t ws_size,
                              hipStream_t stream) {
  (void)in_sizes; (void)n_in; (void)out_size; (void)ws_size;
  const float* st   = (const float*)d_in[0];
  const float* sw   = (const float*)d_in[1];
  const float* ipw  = (const float*)d_in[2];
  const float* cw   = (const float*)d_in[3];
  const float* cb   = (const float*)d_in[4];
  const float* dtb  = (const float*)d_in[5];
  const float* alog = (const float*)d_in[6];
  const float* fcD  = (const float*)d_in[7];
  const float* Dd   = (const float*)d_in[8];
  const float* nw   = (const float*)d_in[9];
  const float* opw  = (const float*)d_in[10];
  const float* tow  = (const float*)d_in[11];
  const float* tob  = (const float*)d_in[12];
  float* out = (float*)d_out;
  unsigned char* ws = (unsigned char*)d_ws;

  float* zx   = (float*)(ws + 0);            // 2*64*2208*4 = 1130496
  float* conv = (float*)(ws + 1130496);      // 2*64*1152*4 = 589824
  float* dtp  = (float*)(ws + 1720320);      // 4*64*16*4   = 16384
  float* yb   = (float*)(ws + 1736704);      // 4*64*1024*4 = 1048576
  float* ynm  = (float*)(ws + 2785280);      // 2*64*1024*4 = 524288
  float* oh   = (float*)(ws + 3309568);      // 2*64*512*4  = 262144
  unsigned short* mfr = (unsigned short*)(ws + 3571712);  // 524288

  k_inproj  <<<dim3(9, 16), 256, 0, stream>>>(st, ipw, zx);
  k_convdt  <<<592, 256, 0, stream>>>(zx, cw, cb, dtb, conv, dtp);
  k_scan    <<<64,  256, 0, stream>>>(conv, dtp, alog, yb);
  k_norm    <<<128, 256, 0, stream>>>(conv, zx, yb, fcD, Dd, nw, ynm);
  k_oproj   <<<dim3(2, 32), 256, 0, stream>>>(ynm, opw, oh);
  k_mfrag   <<<dim3(16, 4), 256, 0, stream>>>(oh, tow, mfr);
  k_out_gemm<<<250, 512, 0, stream>>>(sw, mfr, tob, out);
}

// Round 16
// 242.750 us; speedup vs baseline: 1.5675x; 1.0095x over previous
//
#include <hip/hip_runtime.h>
#include <hip/hip_bf16.h>
#include <math.h>

#define NB 2
#define LL 64
#define NMESH 100000
#define HEADS_O 8
#define DHC 64
#define DMODEL 512
#define DINNER 1024
#define DSTATE 64
#define NH 16
#define CONVDIM 1152
#define DINPROJ 2208
#define DOUT 256
#define NCHUNK 6250   // 100000 / 16, exact

typedef __attribute__((ext_vector_type(8))) short short8v;   // 8 x bf16
typedef __attribute__((ext_vector_type(4))) float f32x4;

__device__ __forceinline__ unsigned short f2bf(float f) {
  union { float f; unsigned u; } v; v.f = f;
  unsigned u = v.u;
  u += 0x7FFFu + ((u >> 16) & 1u);
  return (unsigned short)(u >> 16);
}

__device__ __forceinline__ short8v pack_bf16(float4 lo, float4 hi) {
  short8v r;
  r[0] = (short)f2bf(lo.x); r[1] = (short)f2bf(lo.y);
  r[2] = (short)f2bf(lo.z); r[3] = (short)f2bf(lo.w);
  r[4] = (short)f2bf(hi.x); r[5] = (short)f2bf(hi.y);
  r[6] = (short)f2bf(hi.z); r[7] = (short)f2bf(hi.w);
  return r;
}

__device__ __forceinline__ float dot4(float4 a, const float* b) {
  return a.x*b[0] + a.y*b[1] + a.z*b[2] + a.w*b[3];
}

__device__ __forceinline__ float silu(float s) { return s / (1.f + expf(-s)); }

// ---------------------------------------------------------------- K1: in_proj (weight-streaming)
__global__ void k_inproj(const float* __restrict__ st, const float* __restrict__ w,
                         float* __restrict__ zx) {
  int oc = blockIdx.x;             // 0..8 : o = oc*256 + t
  int blc = blockIdx.y;            // 0..15: bl = blc*8 + r
  int t = threadIdx.x;
  __shared__ float u[8][DMODEL];   // 16 KB
  for (int idx = t; idx < 8*DMODEL; idx += 256) {
    int r = idx >> 9, m = idx & 511;
    int bl = blc*8 + r; int b = bl >> 6, l = bl & 63;
    u[r][m] = st[((size_t)(b*HEADS_O + (m >> 6))*LL + l)*DHC + (m & 63)];
  }
  __syncthreads();
  int o = oc*256 + t;
  if (o < DINPROJ) {
    const float4* wr = (const float4*)(w + (size_t)o*DMODEL);
    float acc[8] = {0,0,0,0,0,0,0,0};
    for (int m4 = 0; m4 < DMODEL/4; ++m4) {
      float4 wv = wr[m4];
      #pragma unroll
      for (int r = 0; r < 8; ++r) acc[r] += dot4(wv, &u[r][m4*4]);
    }
    #pragma unroll
    for (int r = 0; r < 8; ++r)
      zx[(size_t)(blc*8 + r)*DINPROJ + o] = acc[r];
  }
}

// ---------------------------------------------------------------- K2: fused conv+silu AND dt softplus
__global__ void k_convdt(const float* __restrict__ zx, const float* __restrict__ cw,
                         const float* __restrict__ cb, const float* __restrict__ dtb,
                         float* __restrict__ conv_out, float* __restrict__ dtbuf) {
  if (blockIdx.x < 576) {
    int i = blockIdx.x*256 + threadIdx.x;           // < 147456
    int c = i % CONVDIM; int l = (i / CONVDIM) % LL; int b = i / (CONVDIM*LL);
    float s = cb[c];
    #pragma unroll
    for (int k = 0; k < 3; ++k) {
      int tt = l - 1 + k;
      if (tt >= 0 && tt < LL)
        s += cw[c*3 + k] * zx[(size_t)(b*LL + tt)*DINPROJ + DINNER + c];
    }
    conv_out[i] = silu(s);
  } else {
    int i = (blockIdx.x - 576)*256 + threadIdx.x;   // (s*64+l)*16+h, 4096 total
    if (i < 4*LL*NH) {
      int h = i & 15, l = (i >> 4) & 63, s = i >> 10;
      float v;
      if (s < 2)
        v = zx[(size_t)(s*LL + l)*DINPROJ + (DINNER + CONVDIM) + h];
      else
        v = zx[(size_t)((s-2)*LL + (63-l))*DINPROJ + (DINNER + CONVDIM) + 16 + h];
      v += dtb[h];
      dtbuf[i] = (v > 20.f) ? v : log1pf(expf(v));
    }
  }
}

// ---------------------------------------------------------------- K3: SSD scan (parallel form)
__global__ void k_scan(const float* __restrict__ conv_out, const float* __restrict__ dtbuf,
                       const float* __restrict__ A_log, float* __restrict__ ybuf) {
  int blk = blockIdx.x;
  int s = blk >> 4, hh = blk & 15;
  int b = s & 1;
  bool rev = (s >= 2);
  int t = threadIdx.x;
  int wv = t >> 6, lane = t & 63;
  __shared__ float Bs[64*68];
  __shared__ float Cs[64*68];
  __shared__ float Xs[64*64];
  __shared__ float dts[64];
  __shared__ float Dc[64];

  for (int id = t; id < 4096; id += 256) {
    int tt0 = id >> 6, n = id & 63;
    int tt = rev ? (63 - tt0) : tt0;
    size_t base = (size_t)(b*LL + tt) * CONVDIM;
    Xs[tt0*64 + n] = conv_out[base + hh*64 + n];
    Bs[tt0*68 + n] = conv_out[base + DINNER + n];
    Cs[tt0*68 + n] = conv_out[base + DINNER + DSTATE + n];
  }
  if (t < 64) dts[t] = dtbuf[(size_t)(s*LL + t)*NH + hh];
  __syncthreads();
  if (t < 64) {
    float v = dts[t];
    #pragma unroll
    for (int m = 1; m < 64; m <<= 1) {
      float o = __shfl_up(v, m, 64);
      if (lane >= m) v += o;
    }
    Dc[t] = v;
  }
  __syncthreads();
  float A = -expf(A_log[hh]);
  float g[16];
  #pragma unroll
  for (int i = 0; i < 16; ++i) {
    int tt = wv + 4*i;
    int ta = lane;
    float gv = 0.f;
    if (ta <= tt) {
      const float* Br = &Bs[ta*68];
      const float* Cr = &Cs[tt*68];
      float dot = 0.f;
      #pragma unroll
      for (int n4 = 0; n4 < 16; ++n4) {
        float4 bv = *(const float4*)&Br[n4*4];
        float4 cv = *(const float4*)&Cr[n4*4];
        dot += bv.x*cv.x + bv.y*cv.y + bv.z*cv.z + bv.w*cv.w;
      }
      gv = dot * expf(A * (Dc[tt] - Dc[ta])) * dts[ta];
    }
    g[i] = gv;
  }
  __syncthreads();
  #pragma unroll
  for (int i = 0; i < 16; ++i) Bs[(wv + 4*i)*64 + lane] = g[i];
  __syncthreads();
  for (int id = t; id < 4096; id += 256) {
    int tt = id >> 6, p = id & 63;
    float y = 0.f;
    for (int ta = 0; ta <= tt; ++ta) y += Bs[tt*64 + ta] * Xs[ta*64 + p];
    ybuf[(size_t)(s*LL + tt)*DINNER + hh*64 + p] = y;
  }
}

// ---------------------------------------------------------------- K4: norm + out_proj merged (k_oproj's grid)
// 64 blocks (oc 0..1 x blc 0..31), 4 rows each. Norm body (verbatim k_norm
// math) runs 4x sequentially; each opw row o = oc*256+t is then loaded ONCE
// and dotted against all 4 yrow vectors. opw traffic unchanged (64 MB); fcD
// halves (4 MB); ynm round-trip and one launch eliminated.
__global__ void k_normproj(const float* __restrict__ conv_out, const float* __restrict__ zx,
                           const float* __restrict__ yb, const float* __restrict__ fcD,
                           const float* __restrict__ Dd, const float* __restrict__ nw,
                           const float* __restrict__ opw, float* __restrict__ oh) {
  int oc = blockIdx.x;            // 0..1
  int blc = blockIdx.y;           // 0..31
  int t = threadIdx.x;
  __shared__ float xog[DINNER];
  __shared__ float yrow[4][DINNER];  // 16 KB
  __shared__ float diag[NH];
  __shared__ float wsum[4];

  for (int r = 0; r < 4; ++r) {
    int bl = blc*4 + r; int b = bl >> 6, l = bl & 63;
    size_t base = (size_t)bl * CONVDIM;
    for (int c = t; c < DINNER; c += 256) xog[c] = conv_out[base + c];
    __syncthreads();
    {
      int hh = t >> 4, j = t & 15;
      const float* fr = fcD + (size_t)hh*DINNER;
      float acc = 0.f;
      for (int k = 0; k < 64; ++k) acc += xog[j + 16*k] * fr[j + 16*k];
      #pragma unroll
      for (int m = 8; m >= 1; m >>= 1) acc += __shfl_xor(acc, m, 64);
      if (j == 0) diag[hh] = acc + Dd[hh];
    }
    __syncthreads();
    float ss = 0.f;
    float y2v[4];
    #pragma unroll
    for (int i = 0; i < 4; ++i) {
      int c = t + 256*i;
      float yf = (l == 0)  ? 0.f : yb[(size_t)(b*LL + l - 1)*DINNER + c];
      float yw = (l == 63) ? 0.f : yb[(size_t)((2+b)*LL + 62 - l)*DINNER + c];
      float y1 = yf + yw + xog[c]*diag[c >> 6];
      float z = zx[(size_t)bl*DINPROJ + c];
      float y2 = y1 * silu(z);
      y2v[i] = y2;
      ss += y2*y2;
    }
    #pragma unroll
    for (int m = 32; m >= 1; m >>= 1) ss += __shfl_xor(ss, m, 64);
    if ((t & 63) == 0) wsum[t >> 6] = ss;
    __syncthreads();
    float tot = wsum[0] + wsum[1] + wsum[2] + wsum[3];
    float scale = rsqrtf(tot * (1.f/1024.f) + 1e-5f);
    #pragma unroll
    for (int i = 0; i < 4; ++i) {
      int c = t + 256*i;
      yrow[r][c] = y2v[i] * scale * nw[c];
    }
    __syncthreads();
  }
  // ---- out_proj: o = oc*256 + t, one opw row -> 4 rows
  int o = oc*256 + t;
  const float4* wr = (const float4*)(opw + (size_t)o*DINNER);
  float acc[4] = {0,0,0,0};
  for (int k4 = 0; k4 < DINNER/4; ++k4) {
    float4 wv = wr[k4];
    #pragma unroll
    for (int r = 0; r < 4; ++r) acc[r] += dot4(wv, &yrow[r][k4*4]);
  }
  #pragma unroll
  for (int r = 0; r < 4; ++r)
    oh[(size_t)(blc*4 + r)*DMODEL + o] = acc[r];
}

// ---------------------------------------------------------------- K5: build M in B-fragment order (bf16)
__global__ void k_mfrag(const float* __restrict__ oh, const float* __restrict__ tow,
                        unsigned short* __restrict__ mfp) {
  int bgc = blockIdx.x;            // 0..15, bg = bgc*8 + r
  int dc  = blockIdx.y;            // 0..3 : d = dc*64 + dl
  int t = threadIdx.x;
  __shared__ float orow[8][DMODEL]; // 16 KB
  for (int idx = t; idx < 8*DMODEL; idx += 256) {
    int r = idx >> 9, m = idx & 511;
    orow[r][m] = oh[(size_t)(bgc*8 + r)*DMODEL + m];
  }
  __syncthreads();
  #pragma unroll
  for (int ii = 0; ii < 2; ++ii) {
    int idx = t + 256*ii;          // 0..511 -> (h, dl)
    int h = idx >> 6, dl = idx & 63;
    int d = dc*64 + dl;
    const float4* wr = (const float4*)(tow + (size_t)d*DMODEL + h*64);
    float acc[8] = {0,0,0,0,0,0,0,0};
    #pragma unroll
    for (int c4 = 0; c4 < 16; ++c4) {
      float4 wv = wr[c4];
      #pragma unroll
      for (int r = 0; r < 8; ++r) acc[r] += dot4(wv, &orow[r][h*64 + c4*4]);
    }
    #pragma unroll
    for (int r = 0; r < 8; ++r) {
      int bg = bgc*8 + r; int b = bg >> 6, g = bg & 63;
      int kk = g >> 5;
      int ln = (d & 15) | (((g & 31) >> 3) << 4);
      int j = g & 7;
      mfp[((((size_t)(b*HEADS_O + h)*2 + kk)*16 + (d >> 4))*64 + ln)*8 + j] = f2bf(acc[r]);
    }
  }
}

// ---------------------------------------------------------------- K6: amplification-1x GEMM (byte-identical to round 12)
__global__ __launch_bounds__(512, 1) void k_out_gemm(const float* __restrict__ W,
                                                     const unsigned short* __restrict__ mf,
                                                     const float* __restrict__ tob,
                                                     float* __restrict__ out) {
  int bx = blockIdx.x;
  int b    = bx >> 7;
  int base = bx & 127;
  int tid = threadIdx.x;
  int wv = tid >> 6, lane = tid & 63;
  int r16 = lane & 15, kg = lane >> 4;

  __shared__ __align__(16) unsigned short lsA[2][16][512];  // 32 KB bf16 dbuf

  short8v B0[16], B1[16];
  {
    const unsigned short* mfb = mf + (size_t)b*(16*16*512) + lane*8;
    #pragma unroll
    for (int ks = 0; ks < 16; ++ks) {
      B0[ks] = *(const short8v*)(mfb + ((size_t)ks*16 + 2*wv    )*512);
      B1[ks] = *(const short8v*)(mfb + ((size_t)ks*16 + 2*wv + 1)*512);
    }
  }
  float bias0 = tob[wv*32 + r16];
  float bias1 = tob[wv*32 + 16 + r16];

  const float* wbase = W + ((size_t)(b*HEADS_O + wv)*NMESH + r16)*64 + kg*8;

  float4 a0, a1, a2, a3;   // reg set A
  float4 b0, b1, b2, b3;   // reg set B

  #define ALOADS(cc, v0, v1, v2, v3) do { \
    const float* p0 = wbase + (size_t)(cc)*1024; \
    v0 = *(const float4*)p0;        v1 = *(const float4*)(p0 + 4); \
    v2 = *(const float4*)(p0 + 32); v3 = *(const float4*)(p0 + 36); \
  } while (0)
  #define AWR(pp, v0, v1, v2, v3) do { \
    *(short8v*)&lsA[pp][2*wv    ][lane*8] = pack_bf16(v0, v1); \
    *(short8v*)&lsA[pp][2*wv + 1][lane*8] = pack_bf16(v2, v3); \
  } while (0)
  #define MFMA_STORE(pp, cc) do { \
    f32x4 acc0 = (f32x4){0.f,0.f,0.f,0.f}; \
    f32x4 acc1 = (f32x4){0.f,0.f,0.f,0.f}; \
    _Pragma("unroll") \
    for (int ks = 0; ks < 16; ++ks) { \
      short8v af = *(const short8v*)&lsA[pp][ks][lane*8]; \
      acc0 = __builtin_amdgcn_mfma_f32_16x16x32_bf16(af, B0[ks], acc0, 0, 0, 0); \
      acc1 = __builtin_amdgcn_mfma_f32_16x16x32_bf16(af, B1[ks], acc1, 0, 0, 0); \
    } \
    int rb = (cc)*16 + kg*4; \
    int cg = wv*32 + r16; \
    _Pragma("unroll") \
    for (int r = 0; r < 4; ++r) { \
      out[((size_t)b*NMESH + rb + r)*DOUT + cg]      = acc0[r] + bias0; \
      out[((size_t)b*NMESH + rb + r)*DOUT + cg + 16] = acc1[r] + bias1; \
    } \
  } while (0)
  #define KBAR() do { \
    asm volatile("s_waitcnt lgkmcnt(0)" ::: "memory"); \
    __builtin_amdgcn_sched_barrier(0); \
    __builtin_amdgcn_s_barrier(); \
    __builtin_amdgcn_sched_barrier(0); \
  } while (0)

  ALOADS(base, a0, a1, a2, a3);
  AWR(0, a0, a1, a2, a3);
  ALOADS(base + 128, b0, b1, b2, b3);   // always valid: base+128 < 6250
  KBAR();

  int c = base;
  int p = 0;
  for (;;) {
    if (c + 256 < NCHUNK) ALOADS(c + 256, a0, a1, a2, a3);
    __builtin_amdgcn_sched_barrier(0);
    MFMA_STORE(p, c);
    if (c + 128 >= NCHUNK) break;
    __builtin_amdgcn_sched_barrier(0);
    AWR(p ^ 1, b0, b1, b2, b3);
    KBAR();
    p ^= 1; c += 128;
    if (c + 256 < NCHUNK) ALOADS(c + 256, b0, b1, b2, b3);
    __builtin_amdgcn_sched_barrier(0);
    MFMA_STORE(p, c);
    if (c + 128 >= NCHUNK) break;
    __builtin_amdgcn_sched_barrier(0);
    AWR(p ^ 1, a0, a1, a2, a3);
    KBAR();
    p ^= 1; c += 128;
  }
  #undef ALOADS
  #undef AWR
  #undef MFMA_STORE
  #undef KBAR
}

// ----------------------------------------------------------------
extern "C" void kernel_launch(void* const* d_in, const int* in_sizes, int n_in,
                              void* d_out, int out_size, void* d_ws, size_t ws_size,
                              hipStream_t stream) {
  (void)in_sizes; (void)n_in; (void)out_size; (void)ws_size;
  const float* st   = (const float*)d_in[0];
  const float* sw   = (const float*)d_in[1];
  const float* ipw  = (const float*)d_in[2];
  const float* cw   = (const float*)d_in[3];
  const float* cb   = (const float*)d_in[4];
  const float* dtb  = (const float*)d_in[5];
  const float* alog = (const float*)d_in[6];
  const float* fcD  = (const float*)d_in[7];
  const float* Dd   = (const float*)d_in[8];
  const float* nw   = (const float*)d_in[9];
  const float* opw  = (const float*)d_in[10];
  const float* tow  = (const float*)d_in[11];
  const float* tob  = (const float*)d_in[12];
  float* out = (float*)d_out;
  unsigned char* ws = (unsigned char*)d_ws;

  float* zx   = (float*)(ws + 0);            // 2*64*2208*4 = 1130496
  float* conv = (float*)(ws + 1130496);      // 2*64*1152*4 = 589824
  float* dtp  = (float*)(ws + 1720320);      // 4*64*16*4   = 16384
  float* yb   = (float*)(ws + 1736704);      // 4*64*1024*4 = 1048576
  float* oh   = (float*)(ws + 2785280);      // 2*64*512*4  = 262144
  unsigned short* mfr = (unsigned short*)(ws + 3047424);  // 524288

  k_inproj  <<<dim3(9, 16), 256, 0, stream>>>(st, ipw, zx);
  k_convdt  <<<592, 256, 0, stream>>>(zx, cw, cb, dtb, conv, dtp);
  k_scan    <<<64,  256, 0, stream>>>(conv, dtp, alog, yb);
  k_normproj<<<dim3(2, 32), 256, 0, stream>>>(conv, zx, yb, fcD, Dd, nw, opw, oh);
  k_mfrag   <<<dim3(16, 4), 256, 0, stream>>>(oh, tow, mfr);
  k_out_gemm<<<256, 512, 0, stream>>>(sw, mfr, tob, out);
}